// Round 18
// baseline (314.391 us; speedup 1.0000x reference)
//
#include <hip/hip_runtime.h>
#include <hip/hip_bf16.h>

// ---------- bf16 helpers (raw ushort storage) ----------
__device__ __forceinline__ float b2f(unsigned short u) {
    union { float f; unsigned int i; } v; v.i = ((unsigned int)u) << 16; return v.f;
}
__device__ __forceinline__ unsigned short f2b(float f) {
    union { float f; unsigned int i; } v; v.f = f;
    unsigned int i = v.i;
    return (unsigned short)((i + 0x7FFFu + ((i >> 16) & 1u)) >> 16);   // RNE
}

typedef __bf16 bf16x8 __attribute__((ext_vector_type(8)));
typedef float  f32x4  __attribute__((ext_vector_type(4)));

#define MROWS 32

// 256-col LDS tile: row stride 256, XOR-16B swizzle
__device__ __forceinline__ int idx256(int r, int c) {
    return r * 256 + (((c >> 3) ^ (r & 31)) << 3) + (c & 7);
}
// 128-col LDS tile
__device__ __forceinline__ int idx128(int r, int c) {
    return r * 128 + ((((c >> 3) ^ r) & 15) << 3) + (c & 7);
}

// xb: two feature panels xb[p][node][64], p = feature>>6 (R17 layout, neutral).

// ---------- K1: pack weights + zero count/out/scan-state (absorbs memset) ----
// W1,W2 -> hi+lo planes; P1,P2 -> hi only (R13: absmax 0.0117 << 0.036).
__global__ __launch_bounds__(256) void pack_all_init_kernel(
    const float* __restrict__ W1, const float* __restrict__ W2,
    const float* __restrict__ P1, const float* __restrict__ P2,
    unsigned short* __restrict__ W1h, unsigned short* __restrict__ W1l,
    unsigned short* __restrict__ W2h, unsigned short* __restrict__ W2l,
    unsigned short* __restrict__ P1h, unsigned short* __restrict__ P2h,
    int* __restrict__ count, float* __restrict__ out,
    unsigned* __restrict__ state, int M, int nb)
{
    int idx = blockIdx.x * 256 + threadIdx.x;   // over 1024*256 >= M
    if (count && idx < M) { count[idx] = 0; out[idx] = 0.0f; }
    if (state && idx < nb) state[idx] = 0u;
    const float* B; unsigned short *Bh, *Bl; int loc;
    if (idx < 128 * 256)       { B = W1; Bh = W1h; Bl = W1l; loc = idx; }
    else if (idx < 384 * 256)  { B = W2; Bh = W2h; Bl = W2l; loc = idx - 128 * 256; }
    else if (idx < 768 * 256)  { B = P1; Bh = P1h; Bl = nullptr; loc = idx - 384 * 256; }
    else if (idx < 1024 * 256) { B = P2; Bh = P2h; Bl = nullptr; loc = idx - 768 * 256; }
    else return;
    int j    = loc & 7;
    int lane = (loc >> 3) & 63;
    int nt   = (loc >> 9) & 15;
    int kt   = loc >> 13;
    int k = kt * 32 + ((lane >> 4) * 8) + j;
    int n = nt * 16 + (lane & 15);
    float w = B[k * 256 + n];
    unsigned short hi = f2b(w);
    Bh[loc] = hi;
    if (Bl) Bl[loc] = f2b(w - b2f(hi));
}

// ---------- K2: prep+hist: xb panels = bf16([x|t]); hist(count) --------------
__global__ __launch_bounds__(256) void prep_xb_hist_kernel(
    const float* __restrict__ x, const float* __restrict__ t,
    const int* __restrict__ ei,
    unsigned short* __restrict__ xb,
    int* __restrict__ count, int E, int M)
{
    int idx = blockIdx.x * 256 + threadIdx.x;          // over M*128 >= E
    if (idx < M * 128) {
        int i = idx >> 7, j = idx & 127;
        float v = (j < 127) ? x[(size_t)i * 127 + j] : t[i];
        xb[((size_t)(j >> 6) * M + i) * 64 + (j & 63)] = f2b(v);
    }
    if (idx < E) {
        int s = ei[idx];
        int d = ei[E + idx];
        if ((unsigned)s < (unsigned)M && (unsigned)d < (unsigned)M)
            atomicAdd(&count[d], 1);
    }
}

// ---------- fallback prep: agg = 0; out[t_pred] = 0 ----------
__global__ __launch_bounds__(256) void prep_kernel(unsigned short* __restrict__ agg,
                                                   float* __restrict__ out, int M)
{
    int idx = blockIdx.x * 256 + threadIdx.x;
    if (idx < M * 128) agg[idx] = 0;
    if (idx < M) out[idx] = 0.0f;
}

// ---------- fallback scatter: bf16 packed global atomics ----------
__global__ __launch_bounds__(256) void scatter_kernel(
    const int* __restrict__ ei, const float* __restrict__ x,
    const float* __restrict__ t, unsigned short* __restrict__ agg, int E, int M)
{
    int e = blockIdx.x * 8 + (threadIdx.x >> 5);
    if (e >= E) return;
    int lane = threadIdx.x & 31;
    int s = ei[e];
    int d = ei[E + e];
    if ((unsigned)s >= (unsigned)M || (unsigned)d >= (unsigned)M) return;
    int f0 = lane * 4;
    const float* xr = x + (size_t)s * 127;
    float v0 = xr[f0];
    float v1 = xr[f0 + 1];
    float v2 = xr[f0 + 2];
    float v3 = (f0 + 3 < 127) ? xr[f0 + 3] : t[s];
    __hip_bfloat162* dp = (__hip_bfloat162*)(agg + (size_t)d * 128 + f0);
    __hip_bfloat162 a; a.x = __float2bfloat16(v0); a.y = __float2bfloat16(v1);
    __hip_bfloat162 b; b.x = __float2bfloat16(v2); b.y = __float2bfloat16(v3);
    unsafeAtomicAdd(dp,     a);
    unsafeAtomicAdd(dp + 1, b);
}

// ---------- K3: single-pass exclusive scan (decoupled lookback) --------------
// nb = 196 blocks <= 256 CUs -> all co-resident, spin is deadlock-free.
// state[b] = flag(2b) | value(30b): 1=aggregate published, 2=prefix published.
// Values <= 800000 < 2^30. Device-scope atomics (default) handle XCD coherence.
__global__ __launch_bounds__(256) void scan_onepass_kernel(
    const int* __restrict__ count, int* __restrict__ start,
    int* __restrict__ cursor, unsigned* __restrict__ state, int M)
{
    __shared__ int sb[256];
    __shared__ int blockExc;
    int b = blockIdx.x, tid = threadIdx.x;
    int i = b * 256 + tid;
    int v = (i < M) ? count[i] : 0;
    sb[tid] = v;
    __syncthreads();
    for (int off = 1; off < 256; off <<= 1) {
        int a = (tid >= off) ? sb[tid - off] : 0;
        __syncthreads();
        sb[tid] += a;
        __syncthreads();
    }
    int incl  = sb[tid];
    int total = sb[255];
    if (tid == 0) {
        if (b == 0) {
            atomicExch(&state[0], (2u << 30) | (unsigned)total);
            blockExc = 0;
        } else {
            atomicExch(&state[b], (1u << 30) | (unsigned)total);
            int exc = 0;
            int j = b - 1;
            for (;;) {
                unsigned s;
                do { s = atomicAdd(&state[j], 0u); } while ((s >> 30) == 0u);
                exc += (int)(s & 0x3FFFFFFFu);
                if ((s >> 30) == 2u) break;
                --j;
            }
            atomicExch(&state[b], (2u << 30) | (unsigned)(exc + total));
            blockExc = exc;
        }
    }
    __syncthreads();
    int excl = blockExc + incl - v;
    if (i < M) { start[i] = excl; cursor[i] = excl; }
    if (i == M - 1) start[M] = excl + v;
}

// ---------- K4: reorder srcs into dst-sorted CSR order ----------
__global__ __launch_bounds__(256) void reorder_csr_kernel(
    const int* __restrict__ ei, int* __restrict__ cursor,
    int* __restrict__ sorted, int E, int M)
{
    int e = blockIdx.x * 256 + threadIdx.x;
    if (e >= E) return;
    int s = ei[e];
    int d = ei[E + e];
    if ((unsigned)s < (unsigned)M && (unsigned)d < (unsigned)M) {
        int slot = atomicAdd(&cursor[d], 1);
        sorted[slot] = s;
    }
}

// ---------- K5: CSR gather — panel-split, 8 lanes/node, GU=8 -----------------
#define GU 8
template<bool F32AGG>
__global__ __launch_bounds__(256) void gather_csr_kernel(
    const unsigned short* __restrict__ xb, const int* __restrict__ sorted,
    const int* __restrict__ start, void* __restrict__ agg, int M)
{
    int node = blockIdx.x * 32 + (threadIdx.x >> 3);
    if (node >= M) return;
    int l8 = threadIdx.x & 7;                  // 8 lanes x uint4 = 128 B panel row
    int s0 = start[node], s1 = start[node + 1];
    #pragma unroll 1
    for (int p = 0; p < 2; ++p) {
        const unsigned short* xp = xb + (size_t)p * M * 64 + l8 * 8;
        float a[8];
        #pragma unroll
        for (int j = 0; j < 8; ++j) a[j] = 0.f;
        for (int base = s0; base < s1; base += GU) {
            int last = s1 - 1;
            uint4 rv[GU];
            #pragma unroll
            for (int g = 0; g < GU; ++g) {      // all loads in flight first
                int i = base + g;
                int src = sorted[(i < s1) ? i : last];
                rv[g] = *(const uint4*)(xp + (size_t)src * 64);
            }
            #pragma unroll
            for (int g = 0; g < GU; ++g) {
                if (base + g < s1) {
                    a[0] += b2f((unsigned short)(rv[g].x & 0xffff));
                    a[1] += b2f((unsigned short)(rv[g].x >> 16));
                    a[2] += b2f((unsigned short)(rv[g].y & 0xffff));
                    a[3] += b2f((unsigned short)(rv[g].y >> 16));
                    a[4] += b2f((unsigned short)(rv[g].z & 0xffff));
                    a[5] += b2f((unsigned short)(rv[g].z >> 16));
                    a[6] += b2f((unsigned short)(rv[g].w & 0xffff));
                    a[7] += b2f((unsigned short)(rv[g].w >> 16));
                }
            }
        }
        size_t o = (size_t)node * 128 + p * 64 + l8 * 8;
        if (F32AGG) {
            float4 w0; w0.x = a[0]; w0.y = a[1]; w0.z = a[2]; w0.w = a[3];
            float4 w1; w1.x = a[4]; w1.y = a[5]; w1.z = a[6]; w1.w = a[7];
            *(float4*)((float*)agg + o)     = w0;
            *(float4*)((float*)agg + o + 4) = w1;
        } else {
            uint4 w;
            w.x = (unsigned)f2b(a[0]) | ((unsigned)f2b(a[1]) << 16);
            w.y = (unsigned)f2b(a[2]) | ((unsigned)f2b(a[3]) << 16);
            w.z = (unsigned)f2b(a[4]) | ((unsigned)f2b(a[5]) << 16);
            w.w = (unsigned)f2b(a[6]) | ((unsigned)f2b(a[7]) << 16);
            *(uint4*)((unsigned short*)agg + o) = w;
        }
    }
}

// ---------- K6: mega — 4 GEMMs + final dot, 32-row blocks, 16 KB LDS ---------
// W1/W2: split hi+lo (2 MFMAs); P1/P2: hi only (1 MFMA).
// NO __launch_bounds__ min-waves (R9/R11: forced caps -> catastrophic spill).
// R15: do NOT fuse the gather here — phase-lockstep blocks get zero overlap.
template<bool BF16AGG>
__global__ __launch_bounds__(256) void mega_kernel(
    const float* __restrict__ x, const float* __restrict__ t,
    const unsigned short* __restrict__ xb,   // panel layout [2][M][64]
    const void* __restrict__ aggv,
    const unsigned short* __restrict__ W1h, const unsigned short* __restrict__ W1l,
    const float* __restrict__ b1,
    const unsigned short* __restrict__ W2h, const unsigned short* __restrict__ W2l,
    const float* __restrict__ b2,
    const unsigned short* __restrict__ P1h, const float* __restrict__ pb1,
    const unsigned short* __restrict__ P2h, const float* __restrict__ pb2,
    const float* __restrict__ P3, const float* __restrict__ pb3,
    float* __restrict__ out, int M)
{
    __shared__ unsigned short U[MROWS * 256];   // 16 KB: h_in -> h1 -> h -> p1
    __shared__ float red[4 * MROWS];            // 512 B

    const int wave = threadIdx.x >> 6;
    const int lane = threadIdx.x & 63;
    const int lr   = lane & 15;
    const int quad = lane >> 4;
    const int lk   = quad * 8;
    const int rbase = quad * 4;
    const int row0 = blockIdx.x * MROWS;
    const int ntg0 = wave * 4;

    // ---- U[idx128] = bf16(x_in + agg): 32 rows x 128 cols ----
    {
        int r = threadIdx.x >> 3;            // 0..31
        int q = threadIdx.x & 7;             // 0..7, 16 cols each
        int gr = row0 + r; if (gr >= M) gr = M - 1;
        #pragma unroll
        for (int c8 = 0; c8 < 2; ++c8) {
            int c0 = q * 16 + c8 * 8;
            float av[8];
            if (BF16AGG) {
                const unsigned short* ar = (const unsigned short*)aggv + (size_t)gr * 128 + c0;
                uint4 u = *(const uint4*)ar;
                av[0]=b2f((unsigned short)(u.x&0xffff)); av[1]=b2f((unsigned short)(u.x>>16));
                av[2]=b2f((unsigned short)(u.y&0xffff)); av[3]=b2f((unsigned short)(u.y>>16));
                av[4]=b2f((unsigned short)(u.z&0xffff)); av[5]=b2f((unsigned short)(u.z>>16));
                av[6]=b2f((unsigned short)(u.w&0xffff)); av[7]=b2f((unsigned short)(u.w>>16));
            } else {
                const float* ar = (const float*)aggv + (size_t)gr * 128 + c0;
                float4 g0 = *(const float4*)ar, g1 = *(const float4*)(ar + 4);
                av[0]=g0.x; av[1]=g0.y; av[2]=g0.z; av[3]=g0.w;
                av[4]=g1.x; av[5]=g1.y; av[6]=g1.z; av[7]=g1.w;
            }
            union { unsigned short u[8]; uint4 v; } ob;
            if (xb) {
                union { uint4 v; unsigned short u[8]; } xv;
                xv.v = *(const uint4*)(xb + ((size_t)(c0 >> 6) * M + gr) * 64 + (c0 & 63));
                #pragma unroll
                for (int j = 0; j < 8; ++j) ob.u[j] = f2b(b2f(xv.u[j]) + av[j]);
            } else {
                const float* xr = x + (size_t)gr * 127;
                #pragma unroll
                for (int j = 0; j < 8; ++j) {
                    int f = c0 + j;
                    float xval = (f < 127) ? xr[f] : t[gr];
                    ob.u[j] = f2b(xval + av[j]);
                }
            }
            *(uint4*)&U[idx128(r, c0)] = ob.v;
        }
    }
    __syncthreads();

    f32x4 acc[2][4];
    const f32x4 zero = {0.f, 0.f, 0.f, 0.f};

    // ======== stage 1: h1 = relu(h_in @ W1 + b1); U := h1 ========
    #pragma unroll
    for (int nt = 0; nt < 4; ++nt)
        #pragma unroll
        for (int rt = 0; rt < 2; ++rt) acc[rt][nt] = zero;

    for (int kt = 0; kt < 4; ++kt) {
        bf16x8 a[2];
        #pragma unroll
        for (int rt = 0; rt < 2; ++rt)
            a[rt] = *(const bf16x8*)&U[idx128(rt * 16 + lr, kt * 32 + lk)];
        #pragma unroll
        for (int nt = 0; nt < 4; ++nt) {
            size_t bofs = (size_t)((kt * 16 + ntg0 + nt) * 64 + lane) * 8;
            bf16x8 bh = *(const bf16x8*)(W1h + bofs);
            bf16x8 bl = *(const bf16x8*)(W1l + bofs);
            #pragma unroll
            for (int rt = 0; rt < 2; ++rt) {
                acc[rt][nt] = __builtin_amdgcn_mfma_f32_16x16x32_bf16(a[rt], bl, acc[rt][nt], 0, 0, 0);
                acc[rt][nt] = __builtin_amdgcn_mfma_f32_16x16x32_bf16(a[rt], bh, acc[rt][nt], 0, 0, 0);
            }
        }
    }
    __syncthreads();
    #pragma unroll
    for (int nt = 0; nt < 4; ++nt) {
        int col = (ntg0 + nt) * 16 + lr;
        float bv = b1[col];
        #pragma unroll
        for (int rt = 0; rt < 2; ++rt)
            #pragma unroll
            for (int r4 = 0; r4 < 4; ++r4)
                U[idx256(rt * 16 + rbase + r4, col)] = f2b(fmaxf(acc[rt][nt][r4] + bv, 0.f));
    }
    __syncthreads();

    // ======== stage 2: h = tanh(relu(h1 @ W2 + b2)); U := h ========
    #pragma unroll
    for (int nt = 0; nt < 4; ++nt)
        #pragma unroll
        for (int rt = 0; rt < 2; ++rt) acc[rt][nt] = zero;

    for (int kt = 0; kt < 8; ++kt) {
        bf16x8 a[2];
        #pragma unroll
        for (int rt = 0; rt < 2; ++rt)
            a[rt] = *(const bf16x8*)&U[idx256(rt * 16 + lr, kt * 32 + lk)];
        #pragma unroll
        for (int nt = 0; nt < 4; ++nt) {
            size_t bofs = (size_t)((kt * 16 + ntg0 + nt) * 64 + lane) * 8;
            bf16x8 bh = *(const bf16x8*)(W2h + bofs);
            bf16x8 bl = *(const bf16x8*)(W2l + bofs);
            #pragma unroll
            for (int rt = 0; rt < 2; ++rt) {
                acc[rt][nt] = __builtin_amdgcn_mfma_f32_16x16x32_bf16(a[rt], bl, acc[rt][nt], 0, 0, 0);
                acc[rt][nt] = __builtin_amdgcn_mfma_f32_16x16x32_bf16(a[rt], bh, acc[rt][nt], 0, 0, 0);
            }
        }
    }
    __syncthreads();
    #pragma unroll
    for (int nt = 0; nt < 4; ++nt) {
        int col = (ntg0 + nt) * 16 + lr;
        float bv = b2[col];
        #pragma unroll
        for (int rt = 0; rt < 2; ++rt)
            #pragma unroll
            for (int r4 = 0; r4 < 4; ++r4) {
                float v = fmaxf(acc[rt][nt][r4] + bv, 0.f);   // relu∘tanh == tanh∘relu
                float e = __expf(-2.f * v);
                U[idx256(rt * 16 + rbase + r4, col)] = f2b((1.f - e) / (1.f + e));
            }
    }
    __syncthreads();

    // ======== stage 3: p1 = lrelu([h | x_in] @ P1 + pb1); U := p1 ========
    #pragma unroll
    for (int nt = 0; nt < 4; ++nt)
        #pragma unroll
        for (int rt = 0; rt < 2; ++rt) acc[rt][nt] = zero;

    for (int kt = 0; kt < 12; ++kt) {
        bf16x8 a[2];
        if (kt < 8) {
            #pragma unroll
            for (int rt = 0; rt < 2; ++rt)
                a[rt] = *(const bf16x8*)&U[idx256(rt * 16 + lr, kt * 32 + lk)];
        } else if (xb) {
            #pragma unroll
            for (int rt = 0; rt < 2; ++rt) {
                int r = row0 + rt * 16 + lr; if (r >= M) r = M - 1;
                int c0 = (kt - 8) * 32 + lk;
                a[rt] = *(const bf16x8*)(xb + ((size_t)(c0 >> 6) * M + r) * 64 + (c0 & 63));
            }
        } else {
            #pragma unroll
            for (int rt = 0; rt < 2; ++rt) {
                int r = row0 + rt * 16 + lr; if (r >= M) r = M - 1;
                int c0 = (kt - 8) * 32 + lk;
                const float* xr = x + (size_t)r * 127;
                union { unsigned short u[8]; bf16x8 v; } au;
                #pragma unroll
                for (int j = 0; j < 8; ++j) {
                    int f = c0 + j;
                    au.u[j] = f2b((f < 127) ? xr[f] : t[r]);
                }
                a[rt] = au.v;
            }
        }
        #pragma unroll
        for (int nt = 0; nt < 4; ++nt) {
            size_t bofs = (size_t)((kt * 16 + ntg0 + nt) * 64 + lane) * 8;
            bf16x8 bh = *(const bf16x8*)(P1h + bofs);
            #pragma unroll
            for (int rt = 0; rt < 2; ++rt)
                acc[rt][nt] = __builtin_amdgcn_mfma_f32_16x16x32_bf16(a[rt], bh, acc[rt][nt], 0, 0, 0);
        }
    }
    __syncthreads();
    #pragma unroll
    for (int nt = 0; nt < 4; ++nt) {
        int col = (ntg0 + nt) * 16 + lr;
        float bv = pb1[col];
        #pragma unroll
        for (int rt = 0; rt < 2; ++rt)
            #pragma unroll
            for (int r4 = 0; r4 < 4; ++r4) {
                float v = acc[rt][nt][r4] + bv;
                U[idx256(rt * 16 + rbase + r4, col)] = f2b((v > 0.f) ? v : 0.2f * v);
            }
    }
    __syncthreads();

    // ======== stage 4: p2 = lrelu(p1 @ P2 + pb2); pred = p2 . P3 + pb3 ========
    #pragma unroll
    for (int nt = 0; nt < 4; ++nt)
        #pragma unroll
        for (int rt = 0; rt < 2; ++rt) acc[rt][nt] = zero;

    for (int kt = 0; kt < 8; ++kt) {
        bf16x8 a[2];
        #pragma unroll
        for (int rt = 0; rt < 2; ++rt)
            a[rt] = *(const bf16x8*)&U[idx256(rt * 16 + lr, kt * 32 + lk)];
        #pragma unroll
        for (int nt = 0; nt < 4; ++nt) {
            size_t bofs = (size_t)((kt * 16 + ntg0 + nt) * 64 + lane) * 8;
            bf16x8 bh = *(const bf16x8*)(P2h + bofs);
            #pragma unroll
            for (int rt = 0; rt < 2; ++rt)
                acc[rt][nt] = __builtin_amdgcn_mfma_f32_16x16x32_bf16(a[rt], bh, acc[rt][nt], 0, 0, 0);
        }
    }
    float part[2][4];
    #pragma unroll
    for (int rt = 0; rt < 2; ++rt)
        #pragma unroll
        for (int r4 = 0; r4 < 4; ++r4) part[rt][r4] = 0.f;
    #pragma unroll
    for (int nt = 0; nt < 4; ++nt) {
        int col = (ntg0 + nt) * 16 + lr;
        float bv = pb2[col];
        float p3 = P3[col];
        #pragma unroll
        for (int rt = 0; rt < 2; ++rt)
            #pragma unroll
            for (int r4 = 0; r4 < 4; ++r4) {
                float v = acc[rt][nt][r4] + bv;
                v = (v > 0.f) ? v : 0.2f * v;
                part[rt][r4] += v * p3;
            }
    }
    #pragma unroll
    for (int rt = 0; rt < 2; ++rt)
        #pragma unroll
        for (int r4 = 0; r4 < 4; ++r4) {
            float s = part[rt][r4];
            s += __shfl_xor(s, 1);
            s += __shfl_xor(s, 2);
            s += __shfl_xor(s, 4);
            s += __shfl_xor(s, 8);
            if (lr == 0) red[wave * MROWS + rt * 16 + rbase + r4] = s;
        }
    __syncthreads();
    if (threadIdx.x < MROWS) {
        int row = row0 + threadIdx.x;
        if (row < M) {
            float s = red[threadIdx.x] + red[MROWS + threadIdx.x]
                    + red[2 * MROWS + threadIdx.x] + red[3 * MROWS + threadIdx.x] + pb3[0];
            out[M + row] = s;
        }
    }
}

extern "C" void kernel_launch(void* const* d_in, const int* in_sizes, int n_in,
                              void* d_out, int out_size, void* d_ws, size_t ws_size,
                              hipStream_t stream)
{
    const int M = in_sizes[1];                 // 50000
    const int E = in_sizes[3] / 2;             // 800000
    const float* x   = (const float*)d_in[0];
    const float* t   = (const float*)d_in[1];
    const int*   ei  = (const int*)d_in[3];
    const float* W1  = (const float*)d_in[4];
    const float* b1  = (const float*)d_in[5];
    const float* W2  = (const float*)d_in[6];
    const float* b2  = (const float*)d_in[7];
    const float* P1  = (const float*)d_in[8];
    const float* pb1 = (const float*)d_in[9];
    const float* P2  = (const float*)d_in[10];
    const float* pb2 = (const float*)d_in[11];
    const float* P3  = (const float*)d_in[12];
    const float* pb3 = (const float*)d_in[13];
    float* out = (float*)d_out;

    const size_t aggF32 = (size_t)M * 128 * 4;
    const size_t aggBF  = (size_t)M * 128 * 2;
    const size_t xbB    = (size_t)M * 128 * 2;
    const size_t wB     = (size_t)(128 * 2 + 256 * 2 + 384 + 256) * 256 * 2;  // 720 KB
    const size_t sortB  = (size_t)E * 4;
    const int    nb     = (M + 255) / 256;     // 196 scan blocks (<= 256 for co-residency)
    const size_t csrB   = (size_t)(3 * M + 2 + nb) * 4;
    char* ws = (char*)d_ws;
    auto al = [](size_t v) { return (v + 255) & ~(size_t)255; };

    bool tierA = (ws_size >= al(aggF32) + al(xbB) + al(wB) + al(sortB) + al(csrB) + 4096) && nb <= 256;
    bool tierB = (ws_size >= al(aggBF)  + al(xbB) + al(wB) + al(sortB) + al(csrB) + 4096) && nb <= 256;

    size_t aggBytes = tierA ? aggF32 : aggBF;
    void* agg = (void*)ws;
    unsigned short* xb = (unsigned short*)(ws + al(aggBytes));
    unsigned short* W1h = (unsigned short*)((char*)xb + al(xbB));
    unsigned short* W1l = W1h + 128 * 256;
    unsigned short* W2h = W1l + 128 * 256;
    unsigned short* W2l = W2h + 256 * 256;
    unsigned short* P1h = W2l + 256 * 256;
    unsigned short* P2h = P1h + 384 * 256;
    int* sorted = (int*)(P2h + 256 * 256);
    int* count  = sorted + E;
    int* start  = count + M;        // M+1 entries
    int* cursor = start + M + 1;
    unsigned* state = (unsigned*)(cursor + M);

    int gblocks = (M + MROWS - 1) / MROWS;
    int pxb = (M * 128 + 255) / 256;
    int eblocks = (E + 255) / 256;

    if (tierA || tierB) {
        pack_all_init_kernel<<<1024, 256, 0, stream>>>(
            W1, W2, P1, P2, W1h, W1l, W2h, W2l, P1h, P2h,
            count, out, state, M, nb);
        prep_xb_hist_kernel<<<pxb, 256, 0, stream>>>(x, t, ei, xb, count, E, M);
        scan_onepass_kernel<<<nb, 256, 0, stream>>>(count, start, cursor, state, M);
        reorder_csr_kernel<<<eblocks, 256, 0, stream>>>(ei, cursor, sorted, E, M);
        if (tierA) {
            gather_csr_kernel<true><<<(M + 31) / 32, 256, 0, stream>>>(xb, sorted, start, agg, M);
            mega_kernel<false><<<gblocks, 256, 0, stream>>>(
                x, t, xb, agg, W1h, W1l, b1, W2h, W2l, b2,
                P1h, pb1, P2h, pb2, P3, pb3, out, M);
        } else {
            gather_csr_kernel<false><<<(M + 31) / 32, 256, 0, stream>>>(xb, sorted, start, agg, M);
            mega_kernel<true><<<gblocks, 256, 0, stream>>>(
                x, t, xb, agg, W1h, W1l, b1, W2h, W2l, b2,
                P1h, pb1, P2h, pb2, P3, pb3, out, M);
        }
    } else {
        pack_all_init_kernel<<<1024, 256, 0, stream>>>(
            W1, W2, P1, P2, W1h, W1l, W2h, W2l, P1h, P2h,
            nullptr, nullptr, nullptr, M, nb);
        prep_kernel<<<pxb, 256, 0, stream>>>((unsigned short*)agg, out, M);
        scatter_kernel<<<(E + 7) / 8, 256, 0, stream>>>(ei, x, t, (unsigned short*)agg, E, M);
        mega_kernel<false><<<gblocks, 256, 0, stream>>>(
            x, t, nullptr, agg, W1h, W1l, b1, W2h, W2l, b2,
            P1h, pb1, P2h, pb2, P3, pb3, out, M);
    }
}

// Round 19
// 309.537 us; speedup vs baseline: 1.0157x; 1.0157x over previous
//
#include <hip/hip_runtime.h>
#include <hip/hip_bf16.h>

// ---------- bf16 helpers (raw ushort storage) ----------
__device__ __forceinline__ float b2f(unsigned short u) {
    union { float f; unsigned int i; } v; v.i = ((unsigned int)u) << 16; return v.f;
}
__device__ __forceinline__ unsigned short f2b(float f) {
    union { float f; unsigned int i; } v; v.f = f;
    unsigned int i = v.i;
    return (unsigned short)((i + 0x7FFFu + ((i >> 16) & 1u)) >> 16);   // RNE
}

typedef __bf16 bf16x8 __attribute__((ext_vector_type(8)));
typedef float  f32x4  __attribute__((ext_vector_type(4)));

#define MROWS 32

// 256-col LDS tile: row stride 256, XOR-16B swizzle
__device__ __forceinline__ int idx256(int r, int c) {
    return r * 256 + (((c >> 3) ^ (r & 31)) << 3) + (c & 7);
}
// 128-col LDS tile
__device__ __forceinline__ int idx128(int r, int c) {
    return r * 128 + ((((c >> 3) ^ r) & 15) << 3) + (c & 7);
}

// xb: two feature panels xb[p][node][64], p = feature>>6.

// ---------- K1: pack weights + zero count/out/scan-state ----------
__global__ __launch_bounds__(256) void pack_all_init_kernel(
    const float* __restrict__ W1, const float* __restrict__ W2,
    const float* __restrict__ P1, const float* __restrict__ P2,
    unsigned short* __restrict__ W1h, unsigned short* __restrict__ W1l,
    unsigned short* __restrict__ W2h, unsigned short* __restrict__ W2l,
    unsigned short* __restrict__ P1h, unsigned short* __restrict__ P2h,
    int* __restrict__ count, float* __restrict__ out,
    unsigned* __restrict__ state, int M, int nb)
{
    int idx = blockIdx.x * 256 + threadIdx.x;   // over 1024*256 >= M
    if (count && idx < M) { count[idx] = 0; out[idx] = 0.0f; }
    if (state && idx < nb) state[idx] = 0u;
    const float* B; unsigned short *Bh, *Bl; int loc;
    if (idx < 128 * 256)       { B = W1; Bh = W1h; Bl = W1l; loc = idx; }
    else if (idx < 384 * 256)  { B = W2; Bh = W2h; Bl = W2l; loc = idx - 128 * 256; }
    else if (idx < 768 * 256)  { B = P1; Bh = P1h; Bl = nullptr; loc = idx - 384 * 256; }
    else if (idx < 1024 * 256) { B = P2; Bh = P2h; Bl = nullptr; loc = idx - 768 * 256; }
    else return;
    int j    = loc & 7;
    int lane = (loc >> 3) & 63;
    int nt   = (loc >> 9) & 15;
    int kt   = loc >> 13;
    int k = kt * 32 + ((lane >> 4) * 8) + j;
    int n = nt * 16 + (lane & 15);
    float w = B[k * 256 + n];
    unsigned short hi = f2b(w);
    Bh[loc] = hi;
    if (Bl) Bl[loc] = f2b(w - b2f(hi));
}

// ---------- K2: prep+hist: xb panels = bf16([x|t]); hist(count) --------------
__global__ __launch_bounds__(256) void prep_xb_hist_kernel(
    const float* __restrict__ x, const float* __restrict__ t,
    const int* __restrict__ ei,
    unsigned short* __restrict__ xb,
    int* __restrict__ count, int E, int M)
{
    int idx = blockIdx.x * 256 + threadIdx.x;          // over M*128 >= E
    if (idx < M * 128) {
        int i = idx >> 7, j = idx & 127;
        float v = (j < 127) ? x[(size_t)i * 127 + j] : t[i];
        xb[((size_t)(j >> 6) * M + i) * 64 + (j & 63)] = f2b(v);
    }
    if (idx < E) {
        int s = ei[idx];
        int d = ei[E + idx];
        if ((unsigned)s < (unsigned)M && (unsigned)d < (unsigned)M)
            atomicAdd(&count[d], 1);
    }
}

// ---------- fallback prep: agg = 0; out[t_pred] = 0 ----------
__global__ __launch_bounds__(256) void prep_kernel(unsigned short* __restrict__ agg,
                                                   float* __restrict__ out, int M)
{
    int idx = blockIdx.x * 256 + threadIdx.x;
    if (idx < M * 128) agg[idx] = 0;
    if (idx < M) out[idx] = 0.0f;
}

// ---------- fallback scatter: bf16 packed global atomics ----------
__global__ __launch_bounds__(256) void scatter_kernel(
    const int* __restrict__ ei, const float* __restrict__ x,
    const float* __restrict__ t, unsigned short* __restrict__ agg, int E, int M)
{
    int e = blockIdx.x * 8 + (threadIdx.x >> 5);
    if (e >= E) return;
    int lane = threadIdx.x & 31;
    int s = ei[e];
    int d = ei[E + e];
    if ((unsigned)s >= (unsigned)M || (unsigned)d >= (unsigned)M) return;
    int f0 = lane * 4;
    const float* xr = x + (size_t)s * 127;
    float v0 = xr[f0];
    float v1 = xr[f0 + 1];
    float v2 = xr[f0 + 2];
    float v3 = (f0 + 3 < 127) ? xr[f0 + 3] : t[s];
    __hip_bfloat162* dp = (__hip_bfloat162*)(agg + (size_t)d * 128 + f0);
    __hip_bfloat162 a; a.x = __float2bfloat16(v0); a.y = __float2bfloat16(v1);
    __hip_bfloat162 b; b.x = __float2bfloat16(v2); b.y = __float2bfloat16(v3);
    unsafeAtomicAdd(dp,     a);
    unsafeAtomicAdd(dp + 1, b);
}

// ---------- K3: single-pass scan, PARALLEL poll (fixes R18's serial lookback)
// nb = 196 blocks <= 256 CUs -> all co-resident; every block publishes its
// aggregate BEFORE polling -> deadlock-free. Each thread polls ONE slot
// (parallel), then an LDS tree-reduce forms this block's exclusive prefix.
// R18's version had tid==0 serially chaining up to 195 atomic loads (~25-40us).
__global__ __launch_bounds__(256) void scan_fused_kernel(
    const int* __restrict__ count, int* __restrict__ start,
    int* __restrict__ cursor, unsigned* __restrict__ state, int M, int nb)
{
    __shared__ int sb[256];
    __shared__ int pre[256];
    int b = blockIdx.x, tid = threadIdx.x;
    int i = b * 256 + tid;
    int v = (i < M) ? count[i] : 0;
    sb[tid] = v;
    __syncthreads();
    for (int off = 1; off < 256; off <<= 1) {
        int a = (tid >= off) ? sb[tid - off] : 0;
        __syncthreads();
        sb[tid] += a;
        __syncthreads();
    }
    int incl  = sb[tid];
    int total = sb[255];
    if (tid == 0) atomicExch(&state[b], (1u << 30) | (unsigned)total);
    // parallel poll: thread tid owns slot tid (nb <= 256)
    int mine = 0;
    if (tid < nb && tid < b) {
        unsigned s;
        do { s = atomicAdd(&state[tid], 0u); } while ((s >> 30) == 0u);
        mine = (int)(s & 0x3FFFFFFFu);
    }
    pre[tid] = mine;
    __syncthreads();
    #pragma unroll
    for (int off = 128; off > 0; off >>= 1) {
        if (tid < off) pre[tid] += pre[tid + off];
        __syncthreads();
    }
    int excl = pre[0] + incl - v;
    if (i < M) { start[i] = excl; cursor[i] = excl; }
    if (i == M - 1) start[M] = excl + v;
}

// ---------- K4: reorder srcs into dst-sorted CSR order ----------
__global__ __launch_bounds__(256) void reorder_csr_kernel(
    const int* __restrict__ ei, int* __restrict__ cursor,
    int* __restrict__ sorted, int E, int M)
{
    int e = blockIdx.x * 256 + threadIdx.x;
    if (e >= E) return;
    int s = ei[e];
    int d = ei[E + e];
    if ((unsigned)s < (unsigned)M && (unsigned)d < (unsigned)M) {
        int slot = atomicAdd(&cursor[d], 1);
        sorted[slot] = s;
    }
}

// ---------- K5: CSR gather — panel-split, 8 lanes/node, GU=8 -----------------
#define GU 8
template<bool F32AGG>
__global__ __launch_bounds__(256) void gather_csr_kernel(
    const unsigned short* __restrict__ xb, const int* __restrict__ sorted,
    const int* __restrict__ start, void* __restrict__ agg, int M)
{
    int node = blockIdx.x * 32 + (threadIdx.x >> 3);
    if (node >= M) return;
    int l8 = threadIdx.x & 7;                  // 8 lanes x uint4 = 128 B panel row
    int s0 = start[node], s1 = start[node + 1];
    #pragma unroll 1
    for (int p = 0; p < 2; ++p) {
        const unsigned short* xp = xb + (size_t)p * M * 64 + l8 * 8;
        float a[8];
        #pragma unroll
        for (int j = 0; j < 8; ++j) a[j] = 0.f;
        for (int base = s0; base < s1; base += GU) {
            int last = s1 - 1;
            uint4 rv[GU];
            #pragma unroll
            for (int g = 0; g < GU; ++g) {      // all loads in flight first
                int i = base + g;
                int src = sorted[(i < s1) ? i : last];
                rv[g] = *(const uint4*)(xp + (size_t)src * 64);
            }
            #pragma unroll
            for (int g = 0; g < GU; ++g) {
                if (base + g < s1) {
                    a[0] += b2f((unsigned short)(rv[g].x & 0xffff));
                    a[1] += b2f((unsigned short)(rv[g].x >> 16));
                    a[2] += b2f((unsigned short)(rv[g].y & 0xffff));
                    a[3] += b2f((unsigned short)(rv[g].y >> 16));
                    a[4] += b2f((unsigned short)(rv[g].z & 0xffff));
                    a[5] += b2f((unsigned short)(rv[g].z >> 16));
                    a[6] += b2f((unsigned short)(rv[g].w & 0xffff));
                    a[7] += b2f((unsigned short)(rv[g].w >> 16));
                }
            }
        }
        size_t o = (size_t)node * 128 + p * 64 + l8 * 8;
        if (F32AGG) {
            float4 w0; w0.x = a[0]; w0.y = a[1]; w0.z = a[2]; w0.w = a[3];
            float4 w1; w1.x = a[4]; w1.y = a[5]; w1.z = a[6]; w1.w = a[7];
            *(float4*)((float*)agg + o)     = w0;
            *(float4*)((float*)agg + o + 4) = w1;
        } else {
            uint4 w;
            w.x = (unsigned)f2b(a[0]) | ((unsigned)f2b(a[1]) << 16);
            w.y = (unsigned)f2b(a[2]) | ((unsigned)f2b(a[3]) << 16);
            w.z = (unsigned)f2b(a[4]) | ((unsigned)f2b(a[5]) << 16);
            w.w = (unsigned)f2b(a[6]) | ((unsigned)f2b(a[7]) << 16);
            *(uint4*)((unsigned short*)agg + o) = w;
        }
    }
}

// ---------- K6: mega — 4 GEMMs + final dot, 32-row blocks, 16 KB LDS ---------
// W1/W2: split hi+lo (2 MFMAs); P1/P2: hi only (1 MFMA).
// NO __launch_bounds__ min-waves (R9/R11: forced caps -> catastrophic spill).
// R15: do NOT fuse the gather here — phase-lockstep blocks get zero overlap.
template<bool BF16AGG>
__global__ __launch_bounds__(256) void mega_kernel(
    const float* __restrict__ x, const float* __restrict__ t,
    const unsigned short* __restrict__ xb,   // panel layout [2][M][64]
    const void* __restrict__ aggv,
    const unsigned short* __restrict__ W1h, const unsigned short* __restrict__ W1l,
    const float* __restrict__ b1,
    const unsigned short* __restrict__ W2h, const unsigned short* __restrict__ W2l,
    const float* __restrict__ b2,
    const unsigned short* __restrict__ P1h, const float* __restrict__ pb1,
    const unsigned short* __restrict__ P2h, const float* __restrict__ pb2,
    const float* __restrict__ P3, const float* __restrict__ pb3,
    float* __restrict__ out, int M)
{
    __shared__ unsigned short U[MROWS * 256];   // 16 KB: h_in -> h1 -> h -> p1
    __shared__ float red[4 * MROWS];            // 512 B

    const int wave = threadIdx.x >> 6;
    const int lane = threadIdx.x & 63;
    const int lr   = lane & 15;
    const int quad = lane >> 4;
    const int lk   = quad * 8;
    const int rbase = quad * 4;
    const int row0 = blockIdx.x * MROWS;
    const int ntg0 = wave * 4;

    // ---- U[idx128] = bf16(x_in + agg): 32 rows x 128 cols ----
    {
        int r = threadIdx.x >> 3;            // 0..31
        int q = threadIdx.x & 7;             // 0..7, 16 cols each
        int gr = row0 + r; if (gr >= M) gr = M - 1;
        #pragma unroll
        for (int c8 = 0; c8 < 2; ++c8) {
            int c0 = q * 16 + c8 * 8;
            float av[8];
            if (BF16AGG) {
                const unsigned short* ar = (const unsigned short*)aggv + (size_t)gr * 128 + c0;
                uint4 u = *(const uint4*)ar;
                av[0]=b2f((unsigned short)(u.x&0xffff)); av[1]=b2f((unsigned short)(u.x>>16));
                av[2]=b2f((unsigned short)(u.y&0xffff)); av[3]=b2f((unsigned short)(u.y>>16));
                av[4]=b2f((unsigned short)(u.z&0xffff)); av[5]=b2f((unsigned short)(u.z>>16));
                av[6]=b2f((unsigned short)(u.w&0xffff)); av[7]=b2f((unsigned short)(u.w>>16));
            } else {
                const float* ar = (const float*)aggv + (size_t)gr * 128 + c0;
                float4 g0 = *(const float4*)ar, g1 = *(const float4*)(ar + 4);
                av[0]=g0.x; av[1]=g0.y; av[2]=g0.z; av[3]=g0.w;
                av[4]=g1.x; av[5]=g1.y; av[6]=g1.z; av[7]=g1.w;
            }
            union { unsigned short u[8]; uint4 v; } ob;
            if (xb) {
                union { uint4 v; unsigned short u[8]; } xv;
                xv.v = *(const uint4*)(xb + ((size_t)(c0 >> 6) * M + gr) * 64 + (c0 & 63));
                #pragma unroll
                for (int j = 0; j < 8; ++j) ob.u[j] = f2b(b2f(xv.u[j]) + av[j]);
            } else {
                const float* xr = x + (size_t)gr * 127;
                #pragma unroll
                for (int j = 0; j < 8; ++j) {
                    int f = c0 + j;
                    float xval = (f < 127) ? xr[f] : t[gr];
                    ob.u[j] = f2b(xval + av[j]);
                }
            }
            *(uint4*)&U[idx128(r, c0)] = ob.v;
        }
    }
    __syncthreads();

    f32x4 acc[2][4];
    const f32x4 zero = {0.f, 0.f, 0.f, 0.f};

    // ======== stage 1: h1 = relu(h_in @ W1 + b1); U := h1 ========
    #pragma unroll
    for (int nt = 0; nt < 4; ++nt)
        #pragma unroll
        for (int rt = 0; rt < 2; ++rt) acc[rt][nt] = zero;

    for (int kt = 0; kt < 4; ++kt) {
        bf16x8 a[2];
        #pragma unroll
        for (int rt = 0; rt < 2; ++rt)
            a[rt] = *(const bf16x8*)&U[idx128(rt * 16 + lr, kt * 32 + lk)];
        #pragma unroll
        for (int nt = 0; nt < 4; ++nt) {
            size_t bofs = (size_t)((kt * 16 + ntg0 + nt) * 64 + lane) * 8;
            bf16x8 bh = *(const bf16x8*)(W1h + bofs);
            bf16x8 bl = *(const bf16x8*)(W1l + bofs);
            #pragma unroll
            for (int rt = 0; rt < 2; ++rt) {
                acc[rt][nt] = __builtin_amdgcn_mfma_f32_16x16x32_bf16(a[rt], bl, acc[rt][nt], 0, 0, 0);
                acc[rt][nt] = __builtin_amdgcn_mfma_f32_16x16x32_bf16(a[rt], bh, acc[rt][nt], 0, 0, 0);
            }
        }
    }
    __syncthreads();
    #pragma unroll
    for (int nt = 0; nt < 4; ++nt) {
        int col = (ntg0 + nt) * 16 + lr;
        float bv = b1[col];
        #pragma unroll
        for (int rt = 0; rt < 2; ++rt)
            #pragma unroll
            for (int r4 = 0; r4 < 4; ++r4)
                U[idx256(rt * 16 + rbase + r4, col)] = f2b(fmaxf(acc[rt][nt][r4] + bv, 0.f));
    }
    __syncthreads();

    // ======== stage 2: h = tanh(relu(h1 @ W2 + b2)); U := h ========
    #pragma unroll
    for (int nt = 0; nt < 4; ++nt)
        #pragma unroll
        for (int rt = 0; rt < 2; ++rt) acc[rt][nt] = zero;

    for (int kt = 0; kt < 8; ++kt) {
        bf16x8 a[2];
        #pragma unroll
        for (int rt = 0; rt < 2; ++rt)
            a[rt] = *(const bf16x8*)&U[idx256(rt * 16 + lr, kt * 32 + lk)];
        #pragma unroll
        for (int nt = 0; nt < 4; ++nt) {
            size_t bofs = (size_t)((kt * 16 + ntg0 + nt) * 64 + lane) * 8;
            bf16x8 bh = *(const bf16x8*)(W2h + bofs);
            bf16x8 bl = *(const bf16x8*)(W2l + bofs);
            #pragma unroll
            for (int rt = 0; rt < 2; ++rt) {
                acc[rt][nt] = __builtin_amdgcn_mfma_f32_16x16x32_bf16(a[rt], bl, acc[rt][nt], 0, 0, 0);
                acc[rt][nt] = __builtin_amdgcn_mfma_f32_16x16x32_bf16(a[rt], bh, acc[rt][nt], 0, 0, 0);
            }
        }
    }
    __syncthreads();
    #pragma unroll
    for (int nt = 0; nt < 4; ++nt) {
        int col = (ntg0 + nt) * 16 + lr;
        float bv = b2[col];
        #pragma unroll
        for (int rt = 0; rt < 2; ++rt)
            #pragma unroll
            for (int r4 = 0; r4 < 4; ++r4) {
                float v = fmaxf(acc[rt][nt][r4] + bv, 0.f);   // relu∘tanh == tanh∘relu
                float e = __expf(-2.f * v);
                U[idx256(rt * 16 + rbase + r4, col)] = f2b((1.f - e) / (1.f + e));
            }
    }
    __syncthreads();

    // ======== stage 3: p1 = lrelu([h | x_in] @ P1 + pb1); U := p1 ========
    #pragma unroll
    for (int nt = 0; nt < 4; ++nt)
        #pragma unroll
        for (int rt = 0; rt < 2; ++rt) acc[rt][nt] = zero;

    for (int kt = 0; kt < 12; ++kt) {
        bf16x8 a[2];
        if (kt < 8) {
            #pragma unroll
            for (int rt = 0; rt < 2; ++rt)
                a[rt] = *(const bf16x8*)&U[idx256(rt * 16 + lr, kt * 32 + lk)];
        } else if (xb) {
            #pragma unroll
            for (int rt = 0; rt < 2; ++rt) {
                int r = row0 + rt * 16 + lr; if (r >= M) r = M - 1;
                int c0 = (kt - 8) * 32 + lk;
                a[rt] = *(const bf16x8*)(xb + ((size_t)(c0 >> 6) * M + r) * 64 + (c0 & 63));
            }
        } else {
            #pragma unroll
            for (int rt = 0; rt < 2; ++rt) {
                int r = row0 + rt * 16 + lr; if (r >= M) r = M - 1;
                int c0 = (kt - 8) * 32 + lk;
                const float* xr = x + (size_t)r * 127;
                union { unsigned short u[8]; bf16x8 v; } au;
                #pragma unroll
                for (int j = 0; j < 8; ++j) {
                    int f = c0 + j;
                    au.u[j] = f2b((f < 127) ? xr[f] : t[r]);
                }
                a[rt] = au.v;
            }
        }
        #pragma unroll
        for (int nt = 0; nt < 4; ++nt) {
            size_t bofs = (size_t)((kt * 16 + ntg0 + nt) * 64 + lane) * 8;
            bf16x8 bh = *(const bf16x8*)(P1h + bofs);
            #pragma unroll
            for (int rt = 0; rt < 2; ++rt)
                acc[rt][nt] = __builtin_amdgcn_mfma_f32_16x16x32_bf16(a[rt], bh, acc[rt][nt], 0, 0, 0);
        }
    }
    __syncthreads();
    #pragma unroll
    for (int nt = 0; nt < 4; ++nt) {
        int col = (ntg0 + nt) * 16 + lr;
        float bv = pb1[col];
        #pragma unroll
        for (int rt = 0; rt < 2; ++rt)
            #pragma unroll
            for (int r4 = 0; r4 < 4; ++r4) {
                float v = acc[rt][nt][r4] + bv;
                U[idx256(rt * 16 + rbase + r4, col)] = f2b((v > 0.f) ? v : 0.2f * v);
            }
    }
    __syncthreads();

    // ======== stage 4: p2 = lrelu(p1 @ P2 + pb2); pred = p2 . P3 + pb3 ========
    #pragma unroll
    for (int nt = 0; nt < 4; ++nt)
        #pragma unroll
        for (int rt = 0; rt < 2; ++rt) acc[rt][nt] = zero;

    for (int kt = 0; kt < 8; ++kt) {
        bf16x8 a[2];
        #pragma unroll
        for (int rt = 0; rt < 2; ++rt)
            a[rt] = *(const bf16x8*)&U[idx256(rt * 16 + lr, kt * 32 + lk)];
        #pragma unroll
        for (int nt = 0; nt < 4; ++nt) {
            size_t bofs = (size_t)((kt * 16 + ntg0 + nt) * 64 + lane) * 8;
            bf16x8 bh = *(const bf16x8*)(P2h + bofs);
            #pragma unroll
            for (int rt = 0; rt < 2; ++rt)
                acc[rt][nt] = __builtin_amdgcn_mfma_f32_16x16x32_bf16(a[rt], bh, acc[rt][nt], 0, 0, 0);
        }
    }
    float part[2][4];
    #pragma unroll
    for (int rt = 0; rt < 2; ++rt)
        #pragma unroll
        for (int r4 = 0; r4 < 4; ++r4) part[rt][r4] = 0.f;
    #pragma unroll
    for (int nt = 0; nt < 4; ++nt) {
        int col = (ntg0 + nt) * 16 + lr;
        float bv = pb2[col];
        float p3 = P3[col];
        #pragma unroll
        for (int rt = 0; rt < 2; ++rt)
            #pragma unroll
            for (int r4 = 0; r4 < 4; ++r4) {
                float v = acc[rt][nt][r4] + bv;
                v = (v > 0.f) ? v : 0.2f * v;
                part[rt][r4] += v * p3;
            }
    }
    #pragma unroll
    for (int rt = 0; rt < 2; ++rt)
        #pragma unroll
        for (int r4 = 0; r4 < 4; ++r4) {
            float s = part[rt][r4];
            s += __shfl_xor(s, 1);
            s += __shfl_xor(s, 2);
            s += __shfl_xor(s, 4);
            s += __shfl_xor(s, 8);
            if (lr == 0) red[wave * MROWS + rt * 16 + rbase + r4] = s;
        }
    __syncthreads();
    if (threadIdx.x < MROWS) {
        int row = row0 + threadIdx.x;
        if (row < M) {
            float s = red[threadIdx.x] + red[MROWS + threadIdx.x]
                    + red[2 * MROWS + threadIdx.x] + red[3 * MROWS + threadIdx.x] + pb3[0];
            out[M + row] = s;
        }
    }
}

extern "C" void kernel_launch(void* const* d_in, const int* in_sizes, int n_in,
                              void* d_out, int out_size, void* d_ws, size_t ws_size,
                              hipStream_t stream)
{
    const int M = in_sizes[1];                 // 50000
    const int E = in_sizes[3] / 2;             // 800000
    const float* x   = (const float*)d_in[0];
    const float* t   = (const float*)d_in[1];
    const int*   ei  = (const int*)d_in[3];
    const float* W1  = (const float*)d_in[4];
    const float* b1  = (const float*)d_in[5];
    const float* W2  = (const float*)d_in[6];
    const float* b2  = (const float*)d_in[7];
    const float* P1  = (const float*)d_in[8];
    const float* pb1 = (const float*)d_in[9];
    const float* P2  = (const float*)d_in[10];
    const float* pb2 = (const float*)d_in[11];
    const float* P3  = (const float*)d_in[12];
    const float* pb3 = (const float*)d_in[13];
    float* out = (float*)d_out;

    const size_t aggF32 = (size_t)M * 128 * 4;
    const size_t aggBF  = (size_t)M * 128 * 2;
    const size_t xbB    = (size_t)M * 128 * 2;
    const size_t wB     = (size_t)(128 * 2 + 256 * 2 + 384 + 256) * 256 * 2;  // 720 KB
    const size_t sortB  = (size_t)E * 4;
    const int    nb     = (M + 255) / 256;     // 196 scan blocks (<= 256 for co-residency)
    const size_t csrB   = (size_t)(3 * M + 2 + nb) * 4;
    char* ws = (char*)d_ws;
    auto al = [](size_t v) { return (v + 255) & ~(size_t)255; };

    bool tierA = (ws_size >= al(aggF32) + al(xbB) + al(wB) + al(sortB) + al(csrB) + 4096) && nb <= 256;
    bool tierB = (ws_size >= al(aggBF)  + al(xbB) + al(wB) + al(sortB) + al(csrB) + 4096) && nb <= 256;

    size_t aggBytes = tierA ? aggF32 : aggBF;
    void* agg = (void*)ws;
    unsigned short* xb = (unsigned short*)(ws + al(aggBytes));
    unsigned short* W1h = (unsigned short*)((char*)xb + al(xbB));
    unsigned short* W1l = W1h + 128 * 256;
    unsigned short* W2h = W1l + 128 * 256;
    unsigned short* W2l = W2h + 256 * 256;
    unsigned short* P1h = W2l + 256 * 256;
    unsigned short* P2h = P1h + 384 * 256;
    int* sorted = (int*)(P2h + 256 * 256);
    int* count  = sorted + E;
    int* start  = count + M;        // M+1 entries
    int* cursor = start + M + 1;
    unsigned* state = (unsigned*)(cursor + M);

    int gblocks = (M + MROWS - 1) / MROWS;
    int pxb = (M * 128 + 255) / 256;
    int eblocks = (E + 255) / 256;

    if (tierA || tierB) {
        pack_all_init_kernel<<<1024, 256, 0, stream>>>(
            W1, W2, P1, P2, W1h, W1l, W2h, W2l, P1h, P2h,
            count, out, state, M, nb);
        prep_xb_hist_kernel<<<pxb, 256, 0, stream>>>(x, t, ei, xb, count, E, M);
        scan_fused_kernel<<<nb, 256, 0, stream>>>(count, start, cursor, state, M, nb);
        reorder_csr_kernel<<<eblocks, 256, 0, stream>>>(ei, cursor, sorted, E, M);
        if (tierA) {
            gather_csr_kernel<true><<<(M + 31) / 32, 256, 0, stream>>>(xb, sorted, start, agg, M);
            mega_kernel<false><<<gblocks, 256, 0, stream>>>(
                x, t, xb, agg, W1h, W1l, b1, W2h, W2l, b2,
                P1h, pb1, P2h, pb2, P3, pb3, out, M);
        } else {
            gather_csr_kernel<false><<<(M + 31) / 32, 256, 0, stream>>>(xb, sorted, start, agg, M);
            mega_kernel<true><<<gblocks, 256, 0, stream>>>(
                x, t, xb, agg, W1h, W1l, b1, W2h, W2l, b2,
                P1h, pb1, P2h, pb2, P3, pb3, out, M);
        }
    } else {
        pack_all_init_kernel<<<1024, 256, 0, stream>>>(
            W1, W2, P1, P2, W1h, W1l, W2h, W2l, P1h, P2h,
            nullptr, nullptr, nullptr, M, nb);
        prep_kernel<<<pxb, 256, 0, stream>>>((unsigned short*)agg, out, M);
        scatter_kernel<<<(E + 7) / 8, 256, 0, stream>>>(ei, x, t, (unsigned short*)agg, E, M);
        mega_kernel<false><<<gblocks, 256, 0, stream>>>(
            x, t, nullptr, agg, W1h, W1l, b1, W2h, W2l, b2,
            P1h, pb1, P2h, pb2, P3, pb3, out, M);
    }
}